// Round 2
// baseline (456.984 us; speedup 1.0000x reference)
//
#include <hip/hip_runtime.h>
#include <stdint.h>

// LinearCrossAttention on MI355X (gfx950).
// B=4 T=4096 C=1024 H=16 D=64.  All four projections are 16384x1024x1024 GEMMs.
// Pipeline: cvt(x,y,W)->bf16 ; GEMM_Q(+softmax) ; GEMM_K(+softmax+colsum) ; GEMM_V ;
//           kv = k^T v (MFMA, atomic fp32) ; apply: att = q + (q@kv)*Dinv (in-place over q) ;
//           GEMM_P -> fp32 out (+bias).
//
// Buffer plan (ws needs only ~73.1 MiB; big staging lives in d_out):
//   d_out (64 MiB fp32 out, dead until final GEMM):
//     [0,32M)   xb (bf16 x)  -> after GEMM_Q reused as kb (bf16 k)
//     [32,64M)  yb (bf16 y)
//   d_ws:
//     [0,32M)   vb (bf16 v)
//     [32,64M)  qb (bf16 q, becomes att in-place)
//     [64,72M)  Wq,Wk,Wv,Wp bf16 (2 MiB each)
//     [72,73M)  kv fp32 [B*H][64][64]
//     [73M,+16K) kcum fp32 [B][1024]

typedef __attribute__((ext_vector_type(8))) short    bf16x8;
typedef __attribute__((ext_vector_type(4))) float    f32x4;
typedef __attribute__((ext_vector_type(8))) uint16_t u16x8;

typedef __attribute__((address_space(3))) uint32_t        as3_u32;
typedef const __attribute__((address_space(1))) uint32_t  as1_u32;

__device__ __forceinline__ uint16_t f2bf(float f) {
  union { float f; uint32_t u; } v; v.f = f;
  uint32_t r = v.u + 0x7FFFu + ((v.u >> 16) & 1u);
  return (uint16_t)(r >> 16);
}
__device__ __forceinline__ float bf2f(uint16_t u) {
  union { uint32_t u; float f; } v; v.u = ((uint32_t)u) << 16;
  return v.f;
}
// async global->LDS, 16B per lane. LDS dest must be wave-uniform-base + lane*16
// (our addresses are linear-in-lane with stride 16, which is exactly that).
__device__ __forceinline__ void gld16(void* lds, const void* g) {
  __builtin_amdgcn_global_load_lds((as1_u32*)g, (as3_u32*)lds, 16, 0, 0);
}

// ---------------- zero fill (kv + kcum; ws is poisoned 0xAA) -----------------
__global__ void zero_f32(float* __restrict__ p, int n4) {
  const int i = (blockIdx.x * 256 + threadIdx.x) * 4;
  if (i < n4 * 4) {
    f32x4 z = {0.f, 0.f, 0.f, 0.f};
    *(f32x4*)(p + i) = z;
  }
}

// ---------------- fp32 -> bf16 convert (memory-bound, 8 elems/thread) --------
__global__ void cvt_bf16(const float* __restrict__ in, uint16_t* __restrict__ out, int n) {
  int i = (blockIdx.x * 256 + threadIdx.x) * 8;
  const int stride = gridDim.x * 256 * 8;
  for (; i < n; i += stride) {
    f32x4 a = *(const f32x4*)(in + i);
    f32x4 b = *(const f32x4*)(in + i + 4);
    u16x8 r;
    r[0] = f2bf(a[0]); r[1] = f2bf(a[1]); r[2] = f2bf(a[2]); r[3] = f2bf(a[3]);
    r[4] = f2bf(b[0]); r[5] = f2bf(b[1]); r[6] = f2bf(b[2]); r[7] = f2bf(b[3]);
    *(u16x8*)(out + i) = r;
  }
}

// ---------------- 128x128x(BK=32) bf16 GEMM, B^T weights (W is [N][K]) -------
// MODE 0: plain bf16 out (V)
// MODE 1: per-64-col-group softmax, bf16 out (Q)
// MODE 2: softmax + column-sum atomics into kcum (K)
// MODE 3: fp32 out + bias (output projection)
template<int MODE>
__global__ __launch_bounds__(256, 2)
void gemm_bt(const uint16_t* __restrict__ Ag, const uint16_t* __restrict__ Bg,
             uint16_t* __restrict__ outB, float* __restrict__ outF,
             const float* __restrict__ bias, float* __restrict__ kcum)
{
  __shared__ uint16_t Al[128 * 32];
  __shared__ uint16_t Bl[128 * 32];
  const int tid  = threadIdx.x;
  const int lane = tid & 63;
  const int w    = tid >> 6;
  const int wr   = w >> 1, wc = w & 1;
  const int lhi  = lane >> 4, llo = lane & 15;
  const int tM = blockIdx.x >> 3, tN = blockIdx.x & 7;
  const int rBase = tM << 7, cBase = tN << 7;

  f32x4 acc[4][4];
  const f32x4 z = {0.f, 0.f, 0.f, 0.f};
#pragma unroll
  for (int i = 0; i < 4; ++i)
#pragma unroll
    for (int j = 0; j < 4; ++j) acc[i][j] = z;

  // staging: tile rows are 64B (32 bf16); 256 thr * 16B = half a tile (64 rows)
  const int linear = tid * 16;
  const int srow = linear >> 6;   // 0..63
  const int scol = linear & 63;
  const char* gA = (const char*)Ag + ((size_t)(rBase + srow) * 1024) * 2 + scol;
  const char* gB = (const char*)Bg + ((size_t)(cBase + srow) * 1024) * 2 + scol;
  char* lA = (char*)Al + linear;
  char* lB = (char*)Bl + linear;

  for (int kt = 0; kt < 1024; kt += 32) {
    if (kt) __syncthreads();
    gld16(lA,        gA + kt * 2);
    gld16(lA + 4096, gA + kt * 2 + (size_t)64 * 2048);
    gld16(lB,        gB + kt * 2);
    gld16(lB + 4096, gB + kt * 2 + (size_t)64 * 2048);
    __syncthreads();   // compiler emits vmcnt(0) drain before s_barrier
    bf16x8 af[4], bfr[4];
#pragma unroll
    for (int mi = 0; mi < 4; ++mi)
      af[mi] = *(const bf16x8*)&Al[(wr * 64 + mi * 16 + llo) * 32 + lhi * 8];
#pragma unroll
    for (int ni = 0; ni < 4; ++ni)
      bfr[ni] = *(const bf16x8*)&Bl[(wc * 64 + ni * 16 + llo) * 32 + lhi * 8];
#pragma unroll
    for (int mi = 0; mi < 4; ++mi)
#pragma unroll
      for (int ni = 0; ni < 4; ++ni)
        acc[mi][ni] = __builtin_amdgcn_mfma_f32_16x16x32_bf16(af[mi], bfr[ni], acc[mi][ni], 0, 0, 0);
  }

  // ---------------- epilogue ----------------
  const int cW = cBase + wc * 64;   // wave's 64-col block == one head's D
  const int rW = rBase + wr * 64;

  float bv[4];
#pragma unroll
  for (int ni = 0; ni < 4; ++ni) bv[ni] = bias[cW + ni * 16 + llo];
#pragma unroll
  for (int mi = 0; mi < 4; ++mi)
#pragma unroll
    for (int ni = 0; ni < 4; ++ni)
#pragma unroll
      for (int j = 0; j < 4; ++j) acc[mi][ni][j] += bv[ni];

  if (MODE == 1 || MODE == 2) {
    // softmax over the wave's 64 columns, per row. Row (mi, lhi, j)'s 64 values
    // live in {acc[mi][0..3][j]} x {16 lanes sharing lhi}; xor 1/2/4/8 stays in-group.
#pragma unroll
    for (int mi = 0; mi < 4; ++mi)
#pragma unroll
      for (int j = 0; j < 4; ++j) {
        float mx = fmaxf(fmaxf(acc[mi][0][j], acc[mi][1][j]),
                         fmaxf(acc[mi][2][j], acc[mi][3][j]));
        mx = fmaxf(mx, __shfl_xor(mx, 1));
        mx = fmaxf(mx, __shfl_xor(mx, 2));
        mx = fmaxf(mx, __shfl_xor(mx, 4));
        mx = fmaxf(mx, __shfl_xor(mx, 8));
        float e0 = __expf(acc[mi][0][j] - mx);
        float e1 = __expf(acc[mi][1][j] - mx);
        float e2 = __expf(acc[mi][2][j] - mx);
        float e3 = __expf(acc[mi][3][j] - mx);
        float s = e0 + e1 + e2 + e3;
        s += __shfl_xor(s, 1);
        s += __shfl_xor(s, 2);
        s += __shfl_xor(s, 4);
        s += __shfl_xor(s, 8);
        float inv = 1.f / s;
        acc[mi][0][j] = e0 * inv; acc[mi][1][j] = e1 * inv;
        acc[mi][2][j] = e2 * inv; acc[mi][3][j] = e3 * inv;
      }
  }

  float cs[4] = {0.f, 0.f, 0.f, 0.f};
#pragma unroll
  for (int mi = 0; mi < 4; ++mi)
#pragma unroll
    for (int j = 0; j < 4; ++j) {
      const int rG = rW + mi * 16 + lhi * 4 + j;
#pragma unroll
      for (int ni = 0; ni < 4; ++ni) {
        const float v = acc[mi][ni][j];
        const int cG = cW + ni * 16 + llo;
        if (MODE == 3) outF[(size_t)rG * 1024 + cG] = v;
        else           outB[(size_t)rG * 1024 + cG] = f2bf(v);
        if (MODE == 2) cs[ni] += v;
      }
    }

  if (MODE == 2) {
    const int b = rBase >> 12;   // 4096 rows per batch, tiles never straddle
#pragma unroll
    for (int ni = 0; ni < 4; ++ni) {
      float s = cs[ni];
      s += __shfl_xor(s, 16);
      s += __shfl_xor(s, 32);
      if (lhi == 0) atomicAdd(&kcum[b * 1024 + cW + ni * 16 + llo], s);
    }
  }
}

// ---------------- kv[b,h,d,e] = sum_t k[t,d] v[t,e]  (MFMA, T split over blocks)
__global__ __launch_bounds__(256, 2)
void kv_outer(const uint16_t* __restrict__ kb, const uint16_t* __restrict__ vb,
              float* __restrict__ kvg)
{
  __shared__ uint16_t kT[4][64 * 32];   // per-wave [d][t] transposed tile
  __shared__ uint16_t vT[4][64 * 32];   // per-wave [e][t]
  __shared__ float kvs[64 * 64];
  const int tid = threadIdx.x, lane = tid & 63, w = tid >> 6;
  const int lhi = lane >> 4, llo = lane & 15;
  const int head = blockIdx.x >> 3, chunk = blockIdx.x & 7;
  const int b = head >> 4, h = head & 15;

#pragma unroll
  for (int i = 0; i < 16; ++i) kvs[i * 256 + tid] = 0.f;
  __syncthreads();

  f32x4 acc[4][4];
  const f32x4 z = {0.f, 0.f, 0.f, 0.f};
#pragma unroll
  for (int i = 0; i < 4; ++i)
#pragma unroll
    for (int j = 0; j < 4; ++j) acc[i][j] = z;

  const size_t gbase = (size_t)b * 4096 * 1024 + (size_t)h * 64;
  for (int ks = 0; ks < 4; ++ks) {
    const int t0 = chunk * 512 + w * 128 + ks * 32;
    // stage 32t x 64d tiles transposed into per-wave LDS
#pragma unroll
    for (int p = 0; p < 4; ++p) {
      const int idx = (p * 64 + lane) * 8;
      const int t  = idx >> 6;        // 0..31
      const int d0 = idx & 63;        // multiple of 8
      u16x8 kr = *(const u16x8*)&kb[gbase + (size_t)(t0 + t) * 1024 + d0];
      u16x8 vr = *(const u16x8*)&vb[gbase + (size_t)(t0 + t) * 1024 + d0];
#pragma unroll
      for (int jj = 0; jj < 8; ++jj) {
        kT[w][(d0 + jj) * 32 + t] = kr[jj];
        vT[w][(d0 + jj) * 32 + t] = vr[jj];
      }
    }
    // same-wave DS ops are in-order: reads below see the writes above
    bf16x8 af[4], bfr[4];
#pragma unroll
    for (int mi = 0; mi < 4; ++mi)
      af[mi] = *(const bf16x8*)&kT[w][(mi * 16 + llo) * 32 + lhi * 8];
#pragma unroll
    for (int ni = 0; ni < 4; ++ni)
      bfr[ni] = *(const bf16x8*)&vT[w][(ni * 16 + llo) * 32 + lhi * 8];
#pragma unroll
    for (int mi = 0; mi < 4; ++mi)
#pragma unroll
      for (int ni = 0; ni < 4; ++ni)
        acc[mi][ni] = __builtin_amdgcn_mfma_f32_16x16x32_bf16(af[mi], bfr[ni], acc[mi][ni], 0, 0, 0);
  }

  __syncthreads();
  for (int ww = 0; ww < 4; ++ww) {   // serialize waves into kvs (no LDS atomics)
    if (w == ww) {
#pragma unroll
      for (int mi = 0; mi < 4; ++mi)
#pragma unroll
        for (int j = 0; j < 4; ++j) {
          const int d = mi * 16 + lhi * 4 + j;
#pragma unroll
          for (int ni = 0; ni < 4; ++ni)
            kvs[d * 64 + ni * 16 + llo] += acc[mi][ni][j];
        }
    }
    __syncthreads();
  }
  float* dst = kvg + (size_t)head * 4096;
#pragma unroll
  for (int i = 0; i < 16; ++i) atomicAdd(&dst[i * 256 + tid], kvs[i * 256 + tid]);
}

// ---------------- att = q + (q @ kv) * Dinv, in-place over q -----------------
__global__ __launch_bounds__(256, 2)
void apply_attn(uint16_t* __restrict__ qb, const float* __restrict__ kvg,
                const float* __restrict__ kcum)
{
  __shared__ uint16_t ql[128 * 64];   // q tile [t][d]
  __shared__ uint16_t kvl[64 * 64];   // kv transposed [e][d], bf16
  __shared__ float kcs[64];
  __shared__ float dinv[128];
  const int tid = threadIdx.x, lane = tid & 63, w = tid >> 6;
  const int lhi = lane >> 4, llo = lane & 15;
  const int head = blockIdx.x >> 5, tb = blockIdx.x & 31;
  const int b = head >> 4, h = head & 15;
  const int tBase = tb * 128;

  const char* qg = (const char*)qb + (((size_t)b * 4096 + tBase) * 1024 + h * 64) * 2;
#pragma unroll
  for (int p = 0; p < 4; ++p) {
    const int linear = (p * 256 + tid) * 16;
    const int r = linear >> 7, cb2 = linear & 127;
    gld16((char*)ql + linear, qg + (size_t)r * 2048 + cb2);
  }
  const float* kvh = kvg + (size_t)head * 4096;
#pragma unroll
  for (int i = 0; i < 16; ++i) {
    const int idx = i * 256 + tid;
    kvl[(idx & 63) * 64 + (idx >> 6)] = f2bf(kvh[idx]);
  }
  if (tid < 64) kcs[tid] = kcum[b * 1024 + h * 64 + tid];
  __syncthreads();

  // denom[t] = sum_d q[t,d] * kcum[d]; 2 threads per row
  {
    const int r = tid >> 1, half = tid & 1;
    float s = 0.f;
#pragma unroll
    for (int jj = 0; jj < 4; ++jj) {
      u16x8 q8 = *(const u16x8*)&ql[r * 64 + half * 32 + jj * 8];
#pragma unroll
      for (int m = 0; m < 8; ++m) s += bf2f(q8[m]) * kcs[half * 32 + jj * 8 + m];
    }
    s += __shfl_xor(s, 1);
    if (half == 0) dinv[r] = 1.f / s;
  }
  __syncthreads();

  f32x4 acc[2][4];
  const f32x4 z = {0.f, 0.f, 0.f, 0.f};
#pragma unroll
  for (int i = 0; i < 2; ++i)
#pragma unroll
    for (int j = 0; j < 4; ++j) acc[i][j] = z;

#pragma unroll
  for (int ks = 0; ks < 2; ++ks) {
    bf16x8 af[2], bfr[4];
#pragma unroll
    for (int mi = 0; mi < 2; ++mi)
      af[mi] = *(const bf16x8*)&ql[(w * 32 + mi * 16 + llo) * 64 + ks * 32 + lhi * 8];
#pragma unroll
    for (int ni = 0; ni < 4; ++ni)
      bfr[ni] = *(const bf16x8*)&kvl[(ni * 16 + llo) * 64 + ks * 32 + lhi * 8];
#pragma unroll
    for (int mi = 0; mi < 2; ++mi)
#pragma unroll
      for (int ni = 0; ni < 4; ++ni)
        acc[mi][ni] = __builtin_amdgcn_mfma_f32_16x16x32_bf16(af[mi], bfr[ni], acc[mi][ni], 0, 0, 0);
  }

#pragma unroll
  for (int mi = 0; mi < 2; ++mi)
#pragma unroll
    for (int j = 0; j < 4; ++j) {
      const int r = w * 32 + mi * 16 + lhi * 4 + j;
      const float di = dinv[r];
#pragma unroll
      for (int ni = 0; ni < 4; ++ni) {
        const int e = ni * 16 + llo;
        const float o = bf2f(ql[r * 64 + e]) + acc[mi][ni][j] * di;
        qb[((size_t)b * 4096 + tBase + r) * 1024 + h * 64 + e] = f2bf(o);
      }
    }
}

// ---------------- host ----------------
extern "C" void kernel_launch(void* const* d_in, const int* in_sizes, int n_in,
                              void* d_out, int out_size, void* d_ws, size_t ws_size,
                              hipStream_t stream) {
  const float* x  = (const float*)d_in[0];
  const float* y  = (const float*)d_in[1];
  const float* Wq = (const float*)d_in[2];
  const float* bq = (const float*)d_in[3];
  const float* Wk = (const float*)d_in[4];
  const float* bk = (const float*)d_in[5];
  const float* Wv = (const float*)d_in[6];
  const float* bv = (const float*)d_in[7];
  const float* Wp = (const float*)d_in[8];
  const float* bp = (const float*)d_in[9];
  float* out = (float*)d_out;
  char* ws   = (char*)d_ws;
  char* ob   = (char*)d_out;

  constexpr size_t MB = 1024 * 1024;
  constexpr int NELM = 16384 * 1024;          // 16.7M

  // staging in d_out (dead until final GEMM)
  uint16_t* xb  = (uint16_t*)(ob);            // 32 MiB; reused as kb after GEMM_Q
  uint16_t* yb  = (uint16_t*)(ob + 32 * MB);
  uint16_t* kb  = xb;
  // workspace (~73.1 MiB)
  uint16_t* vb  = (uint16_t*)(ws);
  uint16_t* qb  = (uint16_t*)(ws + 32 * MB);
  uint16_t* wqb = (uint16_t*)(ws + 64 * MB);
  uint16_t* wkb = (uint16_t*)(ws + 66 * MB);
  uint16_t* wvb = (uint16_t*)(ws + 68 * MB);
  uint16_t* wpb = (uint16_t*)(ws + 70 * MB);
  float*    kvf = (float*)   (ws + 72 * MB);  // 1 MiB
  float*    kcm = (float*)   (ws + 73 * MB);  // 16 KiB
  (void)ws_size; (void)in_sizes; (void)n_in; (void)out_size;

  // zero kv + kcum (266240 floats = 260*256*4 exactly)
  zero_f32<<<260, 256, 0, stream>>>(kvf, 266240 / 4);

  // fp32 -> bf16
  cvt_bf16<<<2048, 256, 0, stream>>>(x,  xb,  NELM);
  cvt_bf16<<<2048, 256, 0, stream>>>(y,  yb,  NELM);
  cvt_bf16<<<512,  256, 0, stream>>>(Wq, wqb, 1024 * 1024);
  cvt_bf16<<<512,  256, 0, stream>>>(Wk, wkb, 1024 * 1024);
  cvt_bf16<<<512,  256, 0, stream>>>(Wv, wvb, 1024 * 1024);
  cvt_bf16<<<512,  256, 0, stream>>>(Wp, wpb, 1024 * 1024);

  // projections (grid = 128 M-tiles x 8 N-tiles)
  gemm_bt<1><<<1024, 256, 0, stream>>>(xb, wqb, qb, nullptr, bq, nullptr);
  gemm_bt<2><<<1024, 256, 0, stream>>>(yb, wkb, kb, nullptr, bk, kcm);  // kb over dead xb
  gemm_bt<0><<<1024, 256, 0, stream>>>(yb, wvb, vb, nullptr, bv, nullptr);

  kv_outer<<<512, 256, 0, stream>>>(kb, vb, kvf);
  apply_attn<<<2048, 256, 0, stream>>>(qb, kvf, kcm);   // att overwrites qb

  gemm_bt<3><<<1024, 256, 0, stream>>>(qb, wpb, nullptr, out, bp, nullptr);
}

// Round 3
// 398.045 us; speedup vs baseline: 1.1481x; 1.1481x over previous
//
#include <hip/hip_runtime.h>
#include <stdint.h>

// LinearCrossAttention on MI355X (gfx950).  B=4 T=4096 C=1024 H=16 D=64.
// Round 3: 256^2-tile 8-wave GEMM with 4-slot LDS ring + counted vmcnt(4)
// (T3+T4), conflict-free XOR LDS layout (T2), setprio (T5); launch fusion
// (13 -> 5 kernels).
//
// Buffers:
//   d_out: [0,32M) xb (bf16 x) -> reused as kb ; [32,64M) yb (bf16 y)
//   d_ws : [0,32M) vb ; [32,64M) qb(->att) ; [64,72M) Wq,Wk,Wv,Wp bf16 ;
//          [72,73M) kv fp32 ; [73M,+16K) kcum fp32

typedef __attribute__((ext_vector_type(8))) short    bf16x8;
typedef __attribute__((ext_vector_type(4))) float    f32x4;
typedef __attribute__((ext_vector_type(8))) uint16_t u16x8;

typedef __attribute__((address_space(3))) uint32_t        as3_u32;
typedef const __attribute__((address_space(1))) uint32_t  as1_u32;

__device__ __forceinline__ uint16_t f2bf(float f) {
  union { float f; uint32_t u; } v; v.f = f;
  uint32_t r = v.u + 0x7FFFu + ((v.u >> 16) & 1u);
  return (uint16_t)(r >> 16);
}
__device__ __forceinline__ float bf2f(uint16_t u) {
  union { uint32_t u; float f; } v; v.u = ((uint32_t)u) << 16;
  return v.f;
}
// async global->LDS, 16B/lane; LDS dest = wave-uniform base + lane*16.
__device__ __forceinline__ void gld16(void* lds, const void* g) {
  __builtin_amdgcn_global_load_lds((as1_u32*)g, (as3_u32*)lds, 16, 0, 0);
}

// ---------------- fused fp32->bf16 convert of x,y,Wq,Wk,Wv,Wp + zero(kv,kcum)
struct CvtArgs {
  const float* src[6];
  uint16_t*    dst[6];
  float*       zp;      // zero region (kv + kcum)
};
__global__ void cvt_fused(CvtArgs a) {
  // group = 8 fp32. x:2097152, y:2097152, W:131072 x4, zero:33280
  const int total = 4751872;
  int g = blockIdx.x * 256 + threadIdx.x;
  for (; g < total; g += gridDim.x * 256) {
    if (g < 4718592) {
      int seg, off;
      if (g < 4194304) { seg = g >> 21;            off = g & 2097151; }
      else             { int t = g - 4194304; seg = 2 + (t >> 17); off = t & 131071; }
      const float* s = a.src[seg] + (size_t)off * 8;
      f32x4 lo = *(const f32x4*)s;
      f32x4 hi = *(const f32x4*)(s + 4);
      u16x8 r;
      r[0]=f2bf(lo[0]); r[1]=f2bf(lo[1]); r[2]=f2bf(lo[2]); r[3]=f2bf(lo[3]);
      r[4]=f2bf(hi[0]); r[5]=f2bf(hi[1]); r[6]=f2bf(hi[2]); r[7]=f2bf(hi[3]);
      *(u16x8*)(a.dst[seg] + (size_t)off * 8) = r;
    } else {
      float* z = a.zp + (size_t)(g - 4718592) * 8;
      f32x4 zz = {0.f, 0.f, 0.f, 0.f};
      *(f32x4*)z = zz; *(f32x4*)(z + 4) = zz;
    }
  }
}

// ---------------- 256x256 tile GEMM, BK=32, 8 waves, 4-slot LDS ring --------
// C[m][n] = sum_k A[m][k] * W[n][k]  (+bias, +optional softmax/colsum)
// mode: 0 plain bf16 out | 1 softmax bf16 (Q) | 2 softmax+colsum (K) | 3 fp32 (P)
struct GemmPtrs {
  const uint16_t* A;
  const uint16_t* W;
  uint16_t* outB;
  float*    outF;
  const float* bias;
  float*    kcum;
  int       mode;
};
struct GemmArgs { GemmPtrs p[3]; };

// LDS slot: A 16KB + B 16KB. Element (r,k) of a 256x32 tile lives at byte
//   (r>>1)<<7 | ((g ^ ((r>>1)&3))<<5) | ((r&1)<<4 | (k&7)<<1,  g=k>>3.
// -> b128 fragment reads (16 rows, fixed g) hit each bank exactly twice (free).
__device__ __forceinline__ int lds_byte(int r, int g) {
  return ((r >> 1) << 7) | (((g ^ ((r >> 1) & 3))) << 5) | ((r & 1) << 4);
}

#define NKT 32   // K / 32

__global__ __launch_bounds__(512, 2)
void gemm256(GemmArgs args) {
  extern __shared__ char smem[];
  const int idx = blockIdx.x >> 8;
  const GemmPtrs gp = args.p[idx];
  const int bin = blockIdx.x & 255;
  const int swz = (bin & 7) * 32 + (bin >> 3);      // XCD-contiguous chunks
  const int tM = swz >> 2, tN = swz & 3;
  const int rBase = tM << 8, cBase = tN << 8;

  const int tid = threadIdx.x;
  const int lane = tid & 63, w = tid >> 6;
  const int wr = w >> 2, wc = w & 3;
  const int lhi = lane >> 4, llo = lane & 15;

  // ---- staging address precompute (2 A-chunks + 2 B-chunks per K-tile) ----
  // chunk c covers LDS bytes [c*16, c*16+16); decode its (r, g) under the
  // XOR layout and pre-permute the GLOBAL source accordingly (rule #21).
  int pL[2]; size_t goA[2], goB[2];
#pragma unroll
  for (int j = 0; j < 2; ++j) {
    const int p = (j * 512 + tid) * 16;
    const int P = p >> 7, G = (p >> 5) & 3, h = (p >> 4) & 1;
    const int r = P * 2 + h, g = G ^ (P & 3);
    pL[j] = p;
    goA[j] = ((size_t)(rBase + r) * 1024 + g * 8) * 2;
    goB[j] = ((size_t)(cBase + r) * 1024 + g * 8) * 2;
  }
  const char* Ab = (const char*)gp.A;
  const char* Wb = (const char*)gp.W;

  // ---- fragment read offsets (within slot) ----
  int roA[8], roB[4];
#pragma unroll
  for (int mi = 0; mi < 8; ++mi) roA[mi] = lds_byte(wr * 128 + mi * 16 + llo, lhi);
#pragma unroll
  for (int ni = 0; ni < 4; ++ni) roB[ni] = 16384 + lds_byte(wc * 64 + ni * 16 + llo, lhi);

  f32x4 acc[8][4];
  const f32x4 z = {0.f, 0.f, 0.f, 0.f};
#pragma unroll
  for (int i = 0; i < 8; ++i)
#pragma unroll
    for (int j = 0; j < 4; ++j) acc[i][j] = z;

#define STAGE_A(kt, slot) do { char* sb = smem + (slot) * 32768; \
    gld16(sb + pL[0], Ab + goA[0] + (kt) * 64); \
    gld16(sb + pL[1], Ab + goA[1] + (kt) * 64); } while (0)
#define STAGE_B(kt, slot) do { char* sb = smem + (slot) * 32768 + 16384; \
    gld16(sb + pL[0], Wb + goB[0] + (kt) * 64); \
    gld16(sb + pL[1], Wb + goB[1] + (kt) * 64); } while (0)

  // prologue: K-tiles 0,1 into slots 0,1 (order A,A,B,B per tile -> vmcnt math)
  STAGE_A(0, 0); STAGE_B(0, 0);
  STAGE_A(1, 1); STAGE_B(1, 1);

  bf16x8 a0[4], a1[4], bfr[4];
  for (int kt = 0; kt < NKT; ++kt) {
    // own stage(kt) loads landed: everything except stage(kt+1)'s 4 loads.
    if (kt < NKT - 1) asm volatile("s_waitcnt vmcnt(4)" ::: "memory");
    else              asm volatile("s_waitcnt vmcnt(0)" ::: "memory");
    __builtin_amdgcn_sched_barrier(0);
    __builtin_amdgcn_s_barrier();
    __builtin_amdgcn_sched_barrier(0);

    const char* sA = smem + (kt & 3) * 32768;
    const int pslot = (kt + 2) & 3;
    const bool stg = (kt + 2) < NKT;

    // ---- phase 1: frags m0-3 + all B; stage A of kt+2; 16 MFMA ----
#pragma unroll
    for (int mi = 0; mi < 4; ++mi) a0[mi] = *(const bf16x8*)(sA + roA[mi]);
#pragma unroll
    for (int ni = 0; ni < 4; ++ni) bfr[ni] = *(const bf16x8*)(sA + roB[ni]);
    if (stg) STAGE_A(kt + 2, pslot);
    __builtin_amdgcn_s_setprio(1);
#pragma unroll
    for (int mi = 0; mi < 4; ++mi)
#pragma unroll
      for (int ni = 0; ni < 4; ++ni)
        acc[mi][ni] = __builtin_amdgcn_mfma_f32_16x16x32_bf16(a0[mi], bfr[ni], acc[mi][ni], 0, 0, 0);
    __builtin_amdgcn_s_setprio(0);
    __builtin_amdgcn_sched_barrier(0);

    // ---- phase 2: frags m4-7; stage B of kt+2; 16 MFMA ----
#pragma unroll
    for (int mi = 0; mi < 4; ++mi) a1[mi] = *(const bf16x8*)(sA + roA[4 + mi]);
    if (stg) STAGE_B(kt + 2, pslot);
    __builtin_amdgcn_s_setprio(1);
#pragma unroll
    for (int mi = 0; mi < 4; ++mi)
#pragma unroll
      for (int ni = 0; ni < 4; ++ni)
        acc[4 + mi][ni] = __builtin_amdgcn_mfma_f32_16x16x32_bf16(a1[mi], bfr[ni], acc[4 + mi][ni], 0, 0, 0);
    __builtin_amdgcn_s_setprio(0);
  }
#undef STAGE_A
#undef STAGE_B

  // ---------------- epilogue ----------------
  const int mode = gp.mode;
  const int cW = cBase + wc * 64;        // one head group per wave
  const int rW = rBase + wr * 128;

  float bv[4];
#pragma unroll
  for (int ni = 0; ni < 4; ++ni) bv[ni] = gp.bias[cW + ni * 16 + llo];
#pragma unroll
  for (int mi = 0; mi < 8; ++mi)
#pragma unroll
    for (int ni = 0; ni < 4; ++ni)
#pragma unroll
      for (int j = 0; j < 4; ++j) acc[mi][ni][j] += bv[ni];

  if (mode == 1 || mode == 2) {
    // softmax over the wave's 64 cols per row; 16-lane groups (xor 1/2/4/8).
#pragma unroll
    for (int mi = 0; mi < 8; ++mi)
#pragma unroll
      for (int j = 0; j < 4; ++j) {
        float mx = fmaxf(fmaxf(acc[mi][0][j], acc[mi][1][j]),
                         fmaxf(acc[mi][2][j], acc[mi][3][j]));
        mx = fmaxf(mx, __shfl_xor(mx, 1));
        mx = fmaxf(mx, __shfl_xor(mx, 2));
        mx = fmaxf(mx, __shfl_xor(mx, 4));
        mx = fmaxf(mx, __shfl_xor(mx, 8));
        float e0 = __expf(acc[mi][0][j] - mx);
        float e1 = __expf(acc[mi][1][j] - mx);
        float e2 = __expf(acc[mi][2][j] - mx);
        float e3 = __expf(acc[mi][3][j] - mx);
        float s = e0 + e1 + e2 + e3;
        s += __shfl_xor(s, 1);
        s += __shfl_xor(s, 2);
        s += __shfl_xor(s, 4);
        s += __shfl_xor(s, 8);
        float inv = 1.f / s;
        acc[mi][0][j] = e0 * inv; acc[mi][1][j] = e1 * inv;
        acc[mi][2][j] = e2 * inv; acc[mi][3][j] = e3 * inv;
      }
  }

  float cs[4] = {0.f, 0.f, 0.f, 0.f};
#pragma unroll
  for (int mi = 0; mi < 8; ++mi)
#pragma unroll
    for (int j = 0; j < 4; ++j) {
      const int rG = rW + mi * 16 + lhi * 4 + j;
#pragma unroll
      for (int ni = 0; ni < 4; ++ni) {
        const float v = acc[mi][ni][j];
        const int cG = cW + ni * 16 + llo;
        if (mode == 3) gp.outF[(size_t)rG * 1024 + cG] = v;
        else           gp.outB[(size_t)rG * 1024 + cG] = f2bf(v);
        if (mode == 2) cs[ni] += v;
      }
    }

  if (mode == 2) {
    const int b = rBase >> 12;           // 16 tiles per batch, never straddle
#pragma unroll
    for (int ni = 0; ni < 4; ++ni) {
      float s = cs[ni];
      s += __shfl_xor(s, 16);
      s += __shfl_xor(s, 32);
      if (lhi == 0) atomicAdd(&gp.kcum[b * 1024 + cW + ni * 16 + llo], s);
    }
  }
}

// ---------------- kv[b,h,d,e] = sum_t k[t,d] v[t,e]  (MFMA) -----------------
__global__ __launch_bounds__(256, 2)
void kv_outer(const uint16_t* __restrict__ kb, const uint16_t* __restrict__ vb,
              float* __restrict__ kvg)
{
  __shared__ uint16_t kT[4][64 * 32];
  __shared__ uint16_t vT[4][64 * 32];
  __shared__ float kvs[64 * 64];
  const int tid = threadIdx.x, lane = tid & 63, w = tid >> 6;
  const int lhi = lane >> 4, llo = lane & 15;
  const int head = blockIdx.x >> 3, chunk = blockIdx.x & 7;
  const int b = head >> 4, h = head & 15;

#pragma unroll
  for (int i = 0; i < 16; ++i) kvs[i * 256 + tid] = 0.f;
  __syncthreads();

  f32x4 acc[4][4];
  const f32x4 z = {0.f, 0.f, 0.f, 0.f};
#pragma unroll
  for (int i = 0; i < 4; ++i)
#pragma unroll
    for (int j = 0; j < 4; ++j) acc[i][j] = z;

  const size_t gbase = (size_t)b * 4096 * 1024 + (size_t)h * 64;
  for (int ks = 0; ks < 4; ++ks) {
    const int t0 = chunk * 512 + w * 128 + ks * 32;
#pragma unroll
    for (int p = 0; p < 4; ++p) {
      const int idx = (p * 64 + lane) * 8;
      const int t  = idx >> 6;
      const int d0 = idx & 63;
      u16x8 kr = *(const u16x8*)&kb[gbase + (size_t)(t0 + t) * 1024 + d0];
      u16x8 vr = *(const u16x8*)&vb[gbase + (size_t)(t0 + t) * 1024 + d0];
#pragma unroll
      for (int jj = 0; jj < 8; ++jj) {
        kT[w][(d0 + jj) * 32 + t] = kr[jj];
        vT[w][(d0 + jj) * 32 + t] = vr[jj];
      }
    }
    bf16x8 af[4], bfr[4];
#pragma unroll
    for (int mi = 0; mi < 4; ++mi)
      af[mi] = *(const bf16x8*)&kT[w][(mi * 16 + llo) * 32 + lhi * 8];
#pragma unroll
    for (int ni = 0; ni < 4; ++ni)
      bfr[ni] = *(const bf16x8*)&vT[w][(ni * 16 + llo) * 32 + lhi * 8];
#pragma unroll
    for (int mi = 0; mi < 4; ++mi)
#pragma unroll
      for (int ni = 0; ni < 4; ++ni)
        acc[mi][ni] = __builtin_amdgcn_mfma_f32_16x16x32_bf16(af[mi], bfr[ni], acc[mi][ni], 0, 0, 0);
  }

  __syncthreads();
  for (int ww = 0; ww < 4; ++ww) {
    if (w == ww) {
#pragma unroll
      for (int mi = 0; mi < 4; ++mi)
#pragma unroll
        for (int j = 0; j < 4; ++j) {
          const int d = mi * 16 + lhi * 4 + j;
#pragma unroll
          for (int ni = 0; ni < 4; ++ni)
            kvs[d * 64 + ni * 16 + llo] += acc[mi][ni][j];
        }
    }
    __syncthreads();
  }
  float* dst = kvg + (size_t)head * 4096;
#pragma unroll
  for (int i = 0; i < 16; ++i) atomicAdd(&dst[i * 256 + tid], kvs[i * 256 + tid]);
}

// ---------------- att = q + (q @ kv) * Dinv, in-place over q -----------------
__global__ __launch_bounds__(256, 2)
void apply_attn(uint16_t* __restrict__ qb, const float* __restrict__ kvg,
                const float* __restrict__ kcum)
{
  __shared__ uint16_t ql[128 * 64];
  __shared__ uint16_t kvl[64 * 64];
  __shared__ float kcs[64];
  __shared__ float dinv[128];
  const int tid = threadIdx.x, lane = tid & 63, w = tid >> 6;
  const int lhi = lane >> 4, llo = lane & 15;
  const int head = blockIdx.x >> 5, tb = blockIdx.x & 31;
  const int b = head >> 4, h = head & 15;
  const int tBase = tb * 128;

  const char* qg = (const char*)qb + (((size_t)b * 4096 + tBase) * 1024 + h * 64) * 2;
#pragma unroll
  for (int p = 0; p < 4; ++p) {
    const int linear = (p * 256 + tid) * 16;
    const int r = linear >> 7, cb2 = linear & 127;
    gld16((char*)ql + linear, qg + (size_t)r * 2048 + cb2);
  }
  const float* kvh = kvg + (size_t)head * 4096;
#pragma unroll
  for (int i = 0; i < 16; ++i) {
    const int idx = i * 256 + tid;
    kvl[(idx & 63) * 64 + (idx >> 6)] = f2bf(kvh[idx]);
  }
  if (tid < 64) kcs[tid] = kcum[b * 1024 + h * 64 + tid];
  __syncthreads();

  {
    const int r = tid >> 1, half = tid & 1;
    float s = 0.f;
#pragma unroll
    for (int jj = 0; jj < 4; ++jj) {
      u16x8 q8 = *(const u16x8*)&ql[r * 64 + half * 32 + jj * 8];
#pragma unroll
      for (int m = 0; m < 8; ++m) s += bf2f(q8[m]) * kcs[half * 32 + jj * 8 + m];
    }
    s += __shfl_xor(s, 1);
    if (half == 0) dinv[r] = 1.f / s;
  }
  __syncthreads();

  f32x4 acc[2][4];
  const f32x4 z = {0.f, 0.f, 0.f, 0.f};
#pragma unroll
  for (int i = 0; i < 2; ++i)
#pragma unroll
    for (int j = 0; j < 4; ++j) acc[i][j] = z;

#pragma unroll
  for (int ks = 0; ks < 2; ++ks) {
    bf16x8 af[2], bfr[4];
#pragma unroll
    for (int mi = 0; mi < 2; ++mi)
      af[mi] = *(const bf16x8*)&ql[(w * 32 + mi * 16 + llo) * 64 + ks * 32 + lhi * 8];
#pragma unroll
    for (int ni = 0; ni < 4; ++ni)
      bfr[ni] = *(const bf16x8*)&kvl[(ni * 16 + llo) * 64 + ks * 32 + lhi * 8];
#pragma unroll
    for (int mi = 0; mi < 2; ++mi)
#pragma unroll
      for (int ni = 0; ni < 4; ++ni)
        acc[mi][ni] = __builtin_amdgcn_mfma_f32_16x16x32_bf16(af[mi], bfr[ni], acc[mi][ni], 0, 0, 0);
  }

#pragma unroll
  for (int mi = 0; mi < 2; ++mi)
#pragma unroll
    for (int j = 0; j < 4; ++j) {
      const int r = w * 32 + mi * 16 + lhi * 4 + j;
      const float di = dinv[r];
#pragma unroll
      for (int ni = 0; ni < 4; ++ni) {
        const int e = ni * 16 + llo;
        const float o = bf2f(ql[r * 64 + e]) + acc[mi][ni][j] * di;
        qb[((size_t)b * 4096 + tBase + r) * 1024 + h * 64 + e] = f2bf(o);
      }
    }
}

// ---------------- host ----------------
extern "C" void kernel_launch(void* const* d_in, const int* in_sizes, int n_in,
                              void* d_out, int out_size, void* d_ws, size_t ws_size,
                              hipStream_t stream) {
  const float* x  = (const float*)d_in[0];
  const float* y  = (const float*)d_in[1];
  const float* Wq = (const float*)d_in[2];
  const float* bq = (const float*)d_in[3];
  const float* Wk = (const float*)d_in[4];
  const float* bk = (const float*)d_in[5];
  const float* Wv = (const float*)d_in[6];
  const float* bv = (const float*)d_in[7];
  const float* Wp = (const float*)d_in[8];
  const float* bp = (const float*)d_in[9];
  float* out = (float*)d_out;
  char* ws   = (char*)d_ws;
  char* ob   = (char*)d_out;
  (void)in_sizes; (void)n_in; (void)out_size; (void)ws_size;

  constexpr size_t MB = 1024 * 1024;
  uint16_t* xb  = (uint16_t*)(ob);            // -> kb after GEMM_Q
  uint16_t* yb  = (uint16_t*)(ob + 32 * MB);
  uint16_t* kb  = xb;
  uint16_t* vb  = (uint16_t*)(ws);
  uint16_t* qb  = (uint16_t*)(ws + 32 * MB);
  uint16_t* wqb = (uint16_t*)(ws + 64 * MB);
  uint16_t* wkb = (uint16_t*)(ws + 66 * MB);
  uint16_t* wvb = (uint16_t*)(ws + 68 * MB);
  uint16_t* wpb = (uint16_t*)(ws + 70 * MB);
  float*    kvf = (float*)   (ws + 72 * MB);
  float*    kcm = (float*)   (ws + 73 * MB);

  hipFuncSetAttribute((const void*)gemm256,
                      hipFuncAttributeMaxDynamicSharedMemorySize, 131072);

  CvtArgs ca;
  ca.src[0] = x;  ca.dst[0] = xb;
  ca.src[1] = y;  ca.dst[1] = yb;
  ca.src[2] = Wq; ca.dst[2] = wqb;
  ca.src[3] = Wk; ca.dst[3] = wkb;
  ca.src[4] = Wv; ca.dst[4] = wvb;
  ca.src[5] = Wp; ca.dst[5] = wpb;
  ca.zp = kvf;
  cvt_fused<<<2048, 256, 0, stream>>>(ca);

  GemmArgs ga;
  ga.p[0] = {xb, wqb, qb, nullptr, bq, nullptr, 1};   // Q: softmax
  ga.p[1] = {yb, wkb, kb, nullptr, bk, kcm,     2};   // K: softmax+colsum
  ga.p[2] = {yb, wvb, vb, nullptr, bv, nullptr, 0};   // V: plain
  gemm256<<<768, 512, 131072, stream>>>(ga);

  kv_outer<<<512, 256, 0, stream>>>(kb, vb, kvf);
  apply_attn<<<2048, 256, 0, stream>>>(qb, kvf, kcm);

  GemmArgs gp2;
  gp2.p[0] = {qb, wpb, nullptr, out, bp, nullptr, 3}; // P: fp32 out
  gp2.p[1] = gp2.p[0]; gp2.p[2] = gp2.p[0];
  gemm256<<<256, 512, 131072, stream>>>(gp2);
}